// Round 1
// baseline (1225.610 us; speedup 1.0000x reference)
//
#include <hip/hip_runtime.h>
#include <cstddef>

// Problem dims
#define SDIM 256
#define CDIM 64
#define NDIM 2000
#define NPAD 2048
#define TDIM 500

#define MAT  (SDIM*SDIM)   // 65536
#define HMAT (CDIM*SDIM)   // 16384

// ---- workspace layout (float offsets into d_ws) ----  total ~46.1 MB
#define OFF_POW   0u                           // P_1..P_25 : pow[i] = Tm^(i+1)
#define OFF_R2    (OFF_POW + 25u*MAT)          // Tm^50
#define OFF_R4    (OFF_R2 + MAT)               // Tm^100
#define OFF_R8    (OFF_R4 + MAT)               // Tm^200
#define OFF_R16   (OFF_R8 + MAT)               // Tm^400
#define OFF_HEADS (OFF_R16 + MAT)              // H_0..H_19 : h0 (x) Tm^25b
#define OFF_LW    (OFF_HEADS + 20u*HMAT)       // log chain weights [500][64]
#define OFF_LOGE  (OFF_LW + 500u*64u)          // log_E [256][2000]
#define OFF_EXPE  (OFF_LOGE + 256u*2000u)      // exp(log_E - bmax) [256][2048]
#define OFF_BMAXE (OFF_EXPE + 256u*2048u)      // [2048]
#define OFF_EXPH  (OFF_BMAXE + 2048u)          // exp(h - amax) [32000][256]
#define OFF_AMAXH (OFF_EXPH + 500u*64u*256u)   // [32000]

// d_out layout: log_obs [500][2000] | log_obs_ [500][64][2000] | log_hidden [500][64][256]
#define OUT_OBSB  1000000u
#define OUT_HIDB  65000000u

__device__ __forceinline__ float waveMax(float v) {
#pragma unroll
  for (int o = 32; o >= 1; o >>= 1) v = fmaxf(v, __shfl_xor(v, o));
  return v;
}
__device__ __forceinline__ float waveSum(float v) {
#pragma unroll
  for (int o = 32; o >= 1; o >>= 1) v += __shfl_xor(v, o);
  return v;
}

// ---------------- preprocessing: row log_softmax for all four inputs ----------------
__global__ __launch_bounds__(256) void prep_rows(
    const float* __restrict__ si, const float* __restrict__ cw,
    const float* __restrict__ em, const float* __restrict__ tm,
    const float* __restrict__ mask, float* __restrict__ ws) {
  int b = blockIdx.x;
  const float* src; const float* msk = nullptr; float* dst; int len;
  if (b < 64)       { src = si + b*SDIM;                 dst = ws + OFF_HEADS + b*SDIM; len = SDIM; }
  else if (b < 564) { int r = b - 64;  src = cw + r*64;  dst = ws + OFF_LW + r*64;      len = 64;   }
  else if (b < 820) { int r = b - 564; src = tm + (size_t)r*SDIM; dst = ws + OFF_POW + (size_t)r*SDIM; len = SDIM; }
  else              { int r = b - 820; src = em + (size_t)r*NDIM; dst = ws + OFF_LOGE + (size_t)r*NDIM; len = NDIM; msk = mask + (size_t)r*NDIM; }
  int tid = threadIdx.x;
  __shared__ float rA[4], rB[4];
  float m = -INFINITY;
  for (int i = tid; i < len; i += 256) {
    float v = src[i];
    if (msk) v += __logf(msk[i]);
    m = fmaxf(m, v);
  }
  m = waveMax(m);
  if ((tid & 63) == 0) rA[tid >> 6] = m;
  __syncthreads();
  m = fmaxf(fmaxf(rA[0], rA[1]), fmaxf(rA[2], rA[3]));
  float s = 0.f;
  for (int i = tid; i < len; i += 256) {
    float v = src[i];
    if (msk) v += __logf(msk[i]);
    s += __expf(v - m);
  }
  s = waveSum(s);
  if ((tid & 63) == 0) rB[tid >> 6] = s;
  __syncthreads();
  s = rB[0] + rB[1] + rB[2] + rB[3];
  float lse = m + __logf(s);
  for (int i = tid; i < len; i += 256) {
    float v = src[i];
    if (msk) v += __logf(msk[i]);
    dst[i] = v - lse;
  }
}

// expE[k][n] = exp(log_E[k][n] - colmax), padded to 2048 cols with zeros
__global__ __launch_bounds__(256) void prep_expE(float* __restrict__ ws) {
  int n = blockIdx.x * 256 + threadIdx.x;  // 0..2047
  const float* lE = ws + OFF_LOGE;
  float* eE = ws + OFF_EXPE;
  if (n < NDIM) {
    float m = -INFINITY;
    for (int k = 0; k < SDIM; ++k) m = fmaxf(m, lE[(size_t)k*NDIM + n]);
    ws[OFF_BMAXE + n] = m;
    for (int k = 0; k < SDIM; ++k) eE[(size_t)k*NPAD + n] = __expf(lE[(size_t)k*NDIM + n] - m);
  } else {
    ws[OFF_BMAXE + n] = 0.f;
    for (int k = 0; k < SDIM; ++k) eE[(size_t)k*NPAD + n] = 0.f;
  }
}

// ---------------- generic 64x64-tile stabilized log-matmul  C = A (x)log B ----------------
// A: [M][256], B: [256][256], C: [M][256].  Block computes rows r0..r0+63, cols n0..n0+63.
// Row-max of A and col-max of B computed in-block (self-contained, no extra passes).
__device__ void logmm_tile(const float* __restrict__ A, const float* __restrict__ B,
                           float* __restrict__ C, int r0, int n0) {
  __shared__ float As[64][68];   // As[k][r] = exp(A - amax)
  __shared__ float Bs[64][68];   // Bs[k][n] = exp(B - bmax)
  __shared__ float amax[64];
  __shared__ float bmax[64];
  __shared__ float redb[4][64];
  int tid = threadIdx.x;
  {  // amax over K=256 for 64 rows: 4 threads/row
    int r = tid >> 2, part = tid & 3;
    const float* arow = A + (size_t)(r0 + r)*SDIM + part*64;
    float m = arow[0];
    for (int k = 1; k < 64; ++k) m = fmaxf(m, arow[k]);
    m = fmaxf(m, __shfl_xor(m, 1));
    m = fmaxf(m, __shfl_xor(m, 2));
    if (part == 0) amax[r] = m;
  }
  {  // bmax over K=256 for 64 cols: 4 k-parts
    int c = tid & 63, kp = tid >> 6;
    const float* bcol = B + (size_t)kp*64*SDIM + n0 + c;
    float m = bcol[0];
    for (int k = 1; k < 64; ++k) m = fmaxf(m, bcol[(size_t)k*SDIM]);
    redb[kp][c] = m;
  }
  __syncthreads();
  if (tid < 64) bmax[tid] = fmaxf(fmaxf(redb[0][tid], redb[1][tid]),
                                  fmaxf(redb[2][tid], redb[3][tid]));
  float acc[4][4] = {};
  int tc4 = (tid >> 4) << 2, tn4 = (tid & 15) << 2;   // 16x16 threads, 4x4 micro-tile
  for (int kc = 0; kc < 4; ++kc) {
    __syncthreads();
    {
      int rr = tid >> 2, p = tid & 3;
      float am = amax[rr];
      const float* srcA = A + (size_t)(r0 + rr)*SDIM + kc*64 + p*16;
#pragma unroll
      for (int i = 0; i < 16; ++i) As[p*16 + i][rr] = __expf(srcA[i] - am);
    }
    {
      int kk = tid >> 2, p = tid & 3;
      const float* srcB = B + (size_t)(kc*64 + kk)*SDIM + n0 + p*16;
#pragma unroll
      for (int i = 0; i < 16; ++i) Bs[kk][p*16 + i] = __expf(srcB[i] - bmax[p*16 + i]);
    }
    __syncthreads();
#pragma unroll 8
    for (int k = 0; k < 64; ++k) {
      float4 av = *(const float4*)&As[k][tc4];
      float4 bv = *(const float4*)&Bs[k][tn4];
      float a[4] = {av.x, av.y, av.z, av.w};
      float bb[4] = {bv.x, bv.y, bv.z, bv.w};
#pragma unroll
      for (int i = 0; i < 4; ++i)
#pragma unroll
        for (int j = 0; j < 4; ++j) acc[i][j] += a[i]*bb[j];
    }
  }
  float am[4], bm[4];
#pragma unroll
  for (int i = 0; i < 4; ++i) { am[i] = amax[tc4+i]; bm[i] = bmax[tn4+i]; }
#pragma unroll
  for (int i = 0; i < 4; ++i) {
    float4 o;
    o.x = __logf(acc[i][0]) + am[i] + bm[0];
    o.y = __logf(acc[i][1]) + am[i] + bm[1];
    o.z = __logf(acc[i][2]) + am[i] + bm[2];
    o.w = __logf(acc[i][3]) + am[i] + bm[3];
    *(float4*)&C[(size_t)(r0 + tc4 + i)*SDIM + n0 + tn4] = o;
  }
}

struct Jobs {
  int n;
  unsigned aOff[12], bOff[12], cOff[12];
  int M[12];
};

__global__ __launch_bounds__(256) void logmm_kernel(float* __restrict__ ws, Jobs jobs) {
  int j = blockIdx.z;
  if (blockIdx.x * 64 >= jobs.M[j]) return;
  logmm_tile(ws + jobs.aOff[j], ws + jobs.bOff[j], ws + jobs.cOff[j],
             blockIdx.x * 64, blockIdx.y * 64);
}

// fill: h_t = H_b (x)log P_j  (t = 25b + j); j==0 -> copy H_b.  Writes log_hidden in d_out.
__global__ __launch_bounds__(256) void fill_kernel(const float* __restrict__ ws, float* __restrict__ out) {
  int t = blockIdx.y;
  int n0 = blockIdx.x * 64;
  int b = t / 25, j = t % 25;
  const float* H = ws + OFF_HEADS + (size_t)b * HMAT;
  float* C = out + OUT_HIDB + (size_t)t * HMAT;
  if (j == 0) {
    int tid = threadIdx.x;
    int rr = tid >> 2, p = tid & 3;
    const float* s = H + (size_t)rr*SDIM + n0 + p*16;
    float* d = C + (size_t)rr*SDIM + n0 + p*16;
#pragma unroll
    for (int i = 0; i < 16; ++i) d[i] = s[i];
  } else {
    logmm_tile(H, ws + OFF_POW + (size_t)(j-1)*MAT, C, 0, n0);
  }
}

// expH[row][k] = exp(h - rowmax), amaxH[row] = rowmax  (row = t*64 + c)
__global__ __launch_bounds__(256) void expH_kernel(const float* __restrict__ out, float* __restrict__ ws) {
  int row = blockIdx.x;
  int k = threadIdx.x;
  float v = out[OUT_HIDB + (size_t)row*SDIM + k];
  float m = waveMax(v);
  __shared__ float rA[4];
  if ((k & 63) == 0) rA[k >> 6] = m;
  __syncthreads();
  m = fmaxf(fmaxf(rA[0], rA[1]), fmaxf(rA[2], rA[3]));
  ws[OFF_EXPH + (size_t)row*SDIM + k] = __expf(v - m);
  if (k == 0) ws[OFF_AMAXH + row] = m;
}

// emission: per (t, n-tile of 128): log_obs_[t, all 64 c, ntile] and fused
// log_obs[t, ntile] = logsumexp_c(log_obs_ + lw[t,c]).
__global__ __launch_bounds__(256) void emission_kernel(const float* __restrict__ ws, float* __restrict__ out) {
  int t = blockIdx.y;
  int n0 = blockIdx.x * 128;
  const float* eH = ws + OFF_EXPH + (size_t)t*CDIM*SDIM;
  const float* aH = ws + OFF_AMAXH + t*CDIM;
  const float* eE = ws + OFF_EXPE;
  const float* bE = ws + OFF_BMAXE;
  const float* lw = ws + OFF_LW + t*CDIM;
  __shared__ float As[64][68];    // As[k][c]
  __shared__ float Bs[64][132];   // Bs[k][n]
  __shared__ float rmax[8][128];
  __shared__ float rsum[8][128];
  __shared__ float gmax[128];
  int tid = threadIdx.x;
  int tc = tid >> 5;   // 0..7 -> 8 c's each
  int tn = tid & 31;   // 0..31 -> 4 n's each
  float acc[8][4] = {};
  for (int kc = 0; kc < 4; ++kc) {
    __syncthreads();
    {
      int cc = tid >> 2, p = tid & 3;
      const float* srcA = eH + (size_t)cc*SDIM + kc*64 + p*16;
#pragma unroll
      for (int i = 0; i < 16; ++i) As[p*16 + i][cc] = srcA[i];
    }
    {
      int kk = tid >> 2, np = (tid & 3) * 32;
      const float* srcB = eE + (size_t)(kc*64 + kk)*NPAD + n0 + np;
#pragma unroll
      for (int i = 0; i < 32; ++i) Bs[kk][np + i] = srcB[i];
    }
    __syncthreads();
#pragma unroll 4
    for (int k = 0; k < 64; ++k) {
      float4 b4 = *(const float4*)&Bs[k][tn*4];
      float4 a0 = *(const float4*)&As[k][tc*8];
      float4 a1 = *(const float4*)&As[k][tc*8 + 4];
      float a[8] = {a0.x,a0.y,a0.z,a0.w,a1.x,a1.y,a1.z,a1.w};
      float bb[4] = {b4.x,b4.y,b4.z,b4.w};
#pragma unroll
      for (int i = 0; i < 8; ++i)
#pragma unroll
        for (int j = 0; j < 4; ++j) acc[i][j] += a[i]*bb[j];
    }
  }
  float am[8], wv[8];
#pragma unroll
  for (int i = 0; i < 8; ++i) { am[i] = aH[tc*8+i]; wv[i] = lw[tc*8+i]; }
  float bm[4];
#pragma unroll
  for (int j = 0; j < 4; ++j) bm[j] = bE[n0 + tn*4 + j];
  float val[8][4];
#pragma unroll
  for (int i = 0; i < 8; ++i)
#pragma unroll
    for (int j = 0; j < 4; ++j) val[i][j] = __logf(acc[i][j]) + am[i] + bm[j];
  // write log_obs_
  float* obsb = out + OUT_OBSB + (size_t)t*CDIM*NDIM;
  int nb = n0 + tn*4;
#pragma unroll
  for (int i = 0; i < 8; ++i) {
    int c = tc*8 + i;
    float* d = obsb + (size_t)c*NDIM + nb;
    if (nb + 3 < NDIM) {
      *(float4*)d = make_float4(val[i][0], val[i][1], val[i][2], val[i][3]);
    } else {
      for (int j = 0; j < 4; ++j) if (nb + j < NDIM) d[j] = val[i][j];
    }
  }
  // fused logsumexp over c (64) with chain weights
#pragma unroll
  for (int j = 0; j < 4; ++j) {
    float pm = val[0][j] + wv[0];
#pragma unroll
    for (int i = 1; i < 8; ++i) pm = fmaxf(pm, val[i][j] + wv[i]);
    rmax[tc][tn*4 + j] = pm;
  }
  __syncthreads();
  if (tid < 128) {
    float g = rmax[0][tid];
#pragma unroll
    for (int q = 1; q < 8; ++q) g = fmaxf(g, rmax[q][tid]);
    gmax[tid] = g;
  }
  __syncthreads();
#pragma unroll
  for (int j = 0; j < 4; ++j) {
    float g = gmax[tn*4 + j];
    float s = 0.f;
#pragma unroll
    for (int i = 0; i < 8; ++i) s += __expf(val[i][j] + wv[i] - g);
    rsum[tc][tn*4 + j] = s;
  }
  __syncthreads();
  if (tid < 128) {
    int n = n0 + tid;
    if (n < NDIM) {
      float s = rsum[0][tid];
#pragma unroll
      for (int q = 1; q < 8; ++q) s += rsum[q][tid];
      out[(size_t)t*NDIM + n] = __logf(s) + gmax[tid];
    }
  }
}

extern "C" void kernel_launch(void* const* d_in, const int* in_sizes, int n_in,
                              void* d_out, int out_size, void* d_ws, size_t ws_size,
                              hipStream_t stream) {
  const float* si   = (const float*)d_in[0];
  const float* cw   = (const float*)d_in[1];
  const float* em   = (const float*)d_in[2];
  const float* tm   = (const float*)d_in[3];
  const float* mask = (const float*)d_in[4];
  float* out = (float*)d_out;
  float* ws  = (float*)d_ws;
  dim3 blk(256);

  prep_rows<<<dim3(1076), blk, 0, stream>>>(si, cw, em, tm, mask, ws);
  prep_expE<<<dim3(8), blk, 0, stream>>>(ws);

  auto powOff  = [](int j){ return (unsigned)(OFF_POW + (unsigned)j*MAT); };
  auto headOff = [](int b){ return (unsigned)(OFF_HEADS + (unsigned)b*HMAT); };
  Jobs s;

  // powers P_1..P_25 by doubling (pow[i] = Tm^(i+1); pow[0] written by prep)
  s.n = 1; s.aOff[0]=powOff(0); s.bOff[0]=powOff(0); s.cOff[0]=powOff(1); s.M[0]=256;
  logmm_kernel<<<dim3(4,4,1), blk, 0, stream>>>(ws, s);
  s.n = 2;
  s.aOff[0]=powOff(1); s.bOff[0]=powOff(0); s.cOff[0]=powOff(2); s.M[0]=256;
  s.aOff[1]=powOff(1); s.bOff[1]=powOff(1); s.cOff[1]=powOff(3); s.M[1]=256;
  logmm_kernel<<<dim3(4,4,2), blk, 0, stream>>>(ws, s);
  s.n = 4;
  for (int i=0;i<4;++i){ s.aOff[i]=powOff(3); s.bOff[i]=powOff(i); s.cOff[i]=powOff(4+i); s.M[i]=256; }
  logmm_kernel<<<dim3(4,4,4), blk, 0, stream>>>(ws, s);
  s.n = 8;
  for (int i=0;i<8;++i){ s.aOff[i]=powOff(7); s.bOff[i]=powOff(i); s.cOff[i]=powOff(8+i); s.M[i]=256; }
  logmm_kernel<<<dim3(4,4,8), blk, 0, stream>>>(ws, s);
  s.n = 9;
  for (int i=0;i<9;++i){ s.aOff[i]=powOff(15); s.bOff[i]=powOff(i); s.cOff[i]=powOff(16+i); s.M[i]=256; }
  logmm_kernel<<<dim3(4,4,9), blk, 0, stream>>>(ws, s);

  // heads H_b = h0 (x) Tm^25b by doubling; R powers piggyback in the same launches
  s.n = 2;
  s.aOff[0]=headOff(0); s.bOff[0]=powOff(24); s.cOff[0]=headOff(1); s.M[0]=64;
  s.aOff[1]=powOff(24); s.bOff[1]=powOff(24); s.cOff[1]=OFF_R2;     s.M[1]=256;
  logmm_kernel<<<dim3(4,4,2), blk, 0, stream>>>(ws, s);
  s.n = 3;
  s.aOff[0]=headOff(0); s.bOff[0]=OFF_R2; s.cOff[0]=headOff(2); s.M[0]=64;
  s.aOff[1]=headOff(1); s.bOff[1]=OFF_R2; s.cOff[1]=headOff(3); s.M[1]=64;
  s.aOff[2]=OFF_R2;     s.bOff[2]=OFF_R2; s.cOff[2]=OFF_R4;     s.M[2]=256;
  logmm_kernel<<<dim3(4,4,3), blk, 0, stream>>>(ws, s);
  s.n = 5;
  for (int i=0;i<4;++i){ s.aOff[i]=headOff(i); s.bOff[i]=OFF_R4; s.cOff[i]=headOff(4+i); s.M[i]=64; }
  s.aOff[4]=OFF_R4; s.bOff[4]=OFF_R4; s.cOff[4]=OFF_R8; s.M[4]=256;
  logmm_kernel<<<dim3(4,4,5), blk, 0, stream>>>(ws, s);
  s.n = 9;
  for (int i=0;i<8;++i){ s.aOff[i]=headOff(i); s.bOff[i]=OFF_R8; s.cOff[i]=headOff(8+i); s.M[i]=64; }
  s.aOff[8]=OFF_R8; s.bOff[8]=OFF_R8; s.cOff[8]=OFF_R16; s.M[8]=256;
  logmm_kernel<<<dim3(4,4,9), blk, 0, stream>>>(ws, s);
  s.n = 4;
  for (int i=0;i<4;++i){ s.aOff[i]=headOff(i); s.bOff[i]=OFF_R16; s.cOff[i]=headOff(16+i); s.M[i]=64; }
  logmm_kernel<<<dim3(4,4,4), blk, 0, stream>>>(ws, s);

  // parallel fill of all 500 h_t  -> log_hidden (in d_out)
  fill_kernel<<<dim3(4, 500), blk, 0, stream>>>(ws, out);
  // exp(h - rowmax) for the emission GEMM
  expH_kernel<<<dim3(32000), blk, 0, stream>>>(out, ws);
  // big emission log-matmul + fused C-reduction
  emission_kernel<<<dim3(16, 500), blk, 0, stream>>>(ws, out);
}

// Round 3
// 721.446 us; speedup vs baseline: 1.6988x; 1.6988x over previous
//
#include <hip/hip_runtime.h>
#include <cstddef>

typedef unsigned short u16;
typedef float f32x4 __attribute__((ext_vector_type(4)));
typedef short bf16x8 __attribute__((ext_vector_type(8)));

// Problem dims
#define SDIM 256
#define CDIM 64
#define NDIM 2000
#define TDIM 500

#define MAT  (SDIM*SDIM)   // 65536
#define HMAT (CDIM*SDIM)   // 16384

// ---- workspace layout (float offsets into d_ws) ----  ~32.6 MB total
#define OFF_POW    0u                          // P_1..P_25 : pow[i] = Tm^(i+1)
#define OFF_R2     (OFF_POW + 25u*MAT)         // Tm^50
#define OFF_R4     (OFF_R2 + MAT)              // Tm^100
#define OFF_R8     (OFF_R4 + MAT)              // Tm^200
#define OFF_R16    (OFF_R8 + MAT)              // Tm^400
#define OFF_HEADS  (OFF_R16 + MAT)             // H_0..H_19 : h0 (x) Tm^25b  [20][64][256] f32
#define OFF_LW     (OFF_HEADS + 20u*HMAT)      // log chain weights [500][64]
#define OFF_LOGE   (OFF_LW + 32000u)           // log_E [256][2000] f32
#define OFF_BMAXE  (OFF_LOGE + 512000u)        // [2048]
#define OFF_BMAXP  (OFF_BMAXE + 2048u)         // [25][256]
#define OFF_AMAXHD (OFF_BMAXP + 6400u)         // [20][64]
#define OFF_AMAXH  (OFF_AMAXHD + 1280u)        // [500][64]
#define OFF_EXPET  (OFF_AMAXH + 32000u)        // u16 region: expE^T [2048 n][256 k] bf16
#define OFF_EXPPT  (OFF_EXPET + 262144u)       // u16: expP^T [25][256 n][256 k] bf16
#define OFF_EXPHD  (OFF_EXPPT + 819200u)       // u16: expHeads [20][64][256] bf16
#define OFF_EXPHB  (OFF_EXPHD + 163840u)       // u16: expHidden [500][64][256] bf16
// end = 8,155,136 floats = 32.6 MB

// d_out layout: log_obs [500][2000] | log_obs_ [500][64][2000] | log_hidden [500][64][256]
#define OUT_OBSB  1000000u
#define OUT_HIDB  65000000u

__device__ __forceinline__ float waveMax(float v) {
#pragma unroll
  for (int o = 32; o >= 1; o >>= 1) v = fmaxf(v, __shfl_xor(v, o));
  return v;
}
__device__ __forceinline__ float waveSum(float v) {
#pragma unroll
  for (int o = 32; o >= 1; o >>= 1) v += __shfl_xor(v, o);
  return v;
}
__device__ __forceinline__ u16 f2b(float f) {
  union { float f; unsigned u; } x; x.f = f;
  return (u16)((x.u + 0x7fffu + ((x.u >> 16) & 1u)) >> 16);
}

// ---------------- preprocessing: row log_softmax for all four inputs ----------------
__global__ __launch_bounds__(256) void prep_rows(
    const float* __restrict__ si, const float* __restrict__ cw,
    const float* __restrict__ em, const float* __restrict__ tm,
    const float* __restrict__ mask, float* __restrict__ ws) {
  int b = blockIdx.x;
  const float* src; const float* msk = nullptr; float* dst; int len;
  if (b < 64)       { src = si + b*SDIM;                 dst = ws + OFF_HEADS + b*SDIM; len = SDIM; }
  else if (b < 564) { int r = b - 64;  src = cw + r*64;  dst = ws + OFF_LW + r*64;      len = 64;   }
  else if (b < 820) { int r = b - 564; src = tm + (size_t)r*SDIM; dst = ws + OFF_POW + (size_t)r*SDIM; len = SDIM; }
  else              { int r = b - 820; src = em + (size_t)r*NDIM; dst = ws + OFF_LOGE + (size_t)r*NDIM; len = NDIM; msk = mask + (size_t)r*NDIM; }
  int tid = threadIdx.x;
  __shared__ float rA[4], rB[4];
  float m = -INFINITY;
  for (int i = tid; i < len; i += 256) {
    float v = src[i];
    if (msk) v += __logf(msk[i]);
    m = fmaxf(m, v);
  }
  m = waveMax(m);
  if ((tid & 63) == 0) rA[tid >> 6] = m;
  __syncthreads();
  m = fmaxf(fmaxf(rA[0], rA[1]), fmaxf(rA[2], rA[3]));
  float s = 0.f;
  for (int i = tid; i < len; i += 256) {
    float v = src[i];
    if (msk) v += __logf(msk[i]);
    s += __expf(v - m);
  }
  s = waveSum(s);
  if ((tid & 63) == 0) rB[tid >> 6] = s;
  __syncthreads();
  s = rB[0] + rB[1] + rB[2] + rB[3];
  float lse = m + __logf(s);
  for (int i = tid; i < len; i += 256) {
    float v = src[i];
    if (msk) v += __logf(msk[i]);
    dst[i] = v - lse;
  }
}

// ---------------- fp32 logmm tile (chain only; small, known-good) ----------------
__device__ void logmm_tile(const float* __restrict__ A, const float* __restrict__ B,
                           float* __restrict__ C, int r0, int n0) {
  __shared__ float As[64][68];
  __shared__ float Bs[64][68];
  __shared__ float amax[64];
  __shared__ float bmax[64];
  __shared__ float redb[4][64];
  int tid = threadIdx.x;
  {
    int r = tid >> 2, part = tid & 3;
    const float* arow = A + (size_t)(r0 + r)*SDIM + part*64;
    float m = arow[0];
    for (int k = 1; k < 64; ++k) m = fmaxf(m, arow[k]);
    m = fmaxf(m, __shfl_xor(m, 1));
    m = fmaxf(m, __shfl_xor(m, 2));
    if (part == 0) amax[r] = m;
  }
  {
    int c = tid & 63, kp = tid >> 6;
    const float* bcol = B + (size_t)kp*64*SDIM + n0 + c;
    float m = bcol[0];
    for (int k = 1; k < 64; ++k) m = fmaxf(m, bcol[(size_t)k*SDIM]);
    redb[kp][c] = m;
  }
  __syncthreads();
  if (tid < 64) bmax[tid] = fmaxf(fmaxf(redb[0][tid], redb[1][tid]),
                                  fmaxf(redb[2][tid], redb[3][tid]));
  float acc[4][4] = {};
  int tc4 = (tid >> 4) << 2, tn4 = (tid & 15) << 2;
  for (int kc = 0; kc < 4; ++kc) {
    __syncthreads();
    {
      int rr = tid >> 2, p = tid & 3;
      float am = amax[rr];
      const float* srcA = A + (size_t)(r0 + rr)*SDIM + kc*64 + p*16;
#pragma unroll
      for (int i = 0; i < 16; ++i) As[p*16 + i][rr] = __expf(srcA[i] - am);
    }
    {
      int kk = tid >> 2, p = tid & 3;
      const float* srcB = B + (size_t)(kc*64 + kk)*SDIM + n0 + p*16;
#pragma unroll
      for (int i = 0; i < 16; ++i) Bs[kk][p*16 + i] = __expf(srcB[i] - bmax[p*16 + i]);
    }
    __syncthreads();
#pragma unroll 8
    for (int k = 0; k < 64; ++k) {
      float4 av = *(const float4*)&As[k][tc4];
      float4 bv = *(const float4*)&Bs[k][tn4];
      float a[4] = {av.x, av.y, av.z, av.w};
      float bb[4] = {bv.x, bv.y, bv.z, bv.w};
#pragma unroll
      for (int i = 0; i < 4; ++i)
#pragma unroll
        for (int j = 0; j < 4; ++j) acc[i][j] += a[i]*bb[j];
    }
  }
  float am[4], bm[4];
#pragma unroll
  for (int i = 0; i < 4; ++i) { am[i] = amax[tc4+i]; bm[i] = bmax[tn4+i]; }
#pragma unroll
  for (int i = 0; i < 4; ++i) {
    float4 o;
    o.x = __logf(acc[i][0]) + am[i] + bm[0];
    o.y = __logf(acc[i][1]) + am[i] + bm[1];
    o.z = __logf(acc[i][2]) + am[i] + bm[2];
    o.w = __logf(acc[i][3]) + am[i] + bm[3];
    *(float4*)&C[(size_t)(r0 + tc4 + i)*SDIM + n0 + tn4] = o;
  }
}

struct Jobs {
  int n;
  unsigned aOff[12], bOff[12], cOff[12];
  int M[12];
};

__global__ __launch_bounds__(256) void logmm_kernel(float* __restrict__ ws, Jobs jobs) {
  int j = blockIdx.z;
  if (blockIdx.x * 64 >= jobs.M[j]) return;
  logmm_tile(ws + jobs.aOff[j], ws + jobs.bOff[j], ws + jobs.cOff[j],
             blockIdx.x * 64, blockIdx.y * 64);
}

// ---------------- exp-transpose prep: dst[n][k] = bf16(exp(src[k][n]-colmax)) ----------------
__global__ __launch_bounds__(256) void prep_expT(
    const float* __restrict__ srcBase, int ldn, int nReal, unsigned srcJStride,
    u16* __restrict__ dstBase, unsigned dstJStride,
    float* __restrict__ bmaxBase, unsigned bmaxJStride) {
  const float* src = srcBase + (size_t)blockIdx.y * srcJStride;
  u16* dst = dstBase + (size_t)blockIdx.y * dstJStride;
  float* bmax = bmaxBase + (size_t)blockIdx.y * bmaxJStride;
  int nb = blockIdx.x * 64;
  int t = threadIdx.x;
  __shared__ float red[4][64];
  __shared__ float bms[64];
  {
    int n = nb + (t & 63), kp = t >> 6;
    float m = -INFINITY;
    if (n < nReal) {
      for (int k = kp*64; k < kp*64 + 64; ++k) m = fmaxf(m, src[(size_t)k*ldn + n]);
    }
    red[kp][t & 63] = m;
  }
  __syncthreads();
  if (t < 64) {
    float mm = fmaxf(fmaxf(red[0][t], red[1][t]), fmaxf(red[2][t], red[3][t]));
    bms[t] = mm;
    bmax[nb + t] = (nb + t < nReal) ? mm : 0.f;
  }
  __syncthreads();
  int rn = nb + (t >> 2);
  int kq = (t & 3) * 64;
  float bm = bms[t >> 2];
  bool valid = (rn < nReal);
  unsigned outw[32];
#pragma unroll
  for (int i = 0; i < 32; ++i) {
    float v0 = valid ? __expf(src[(size_t)(kq + 2*i)*ldn + rn] - bm) : 0.f;
    float v1 = valid ? __expf(src[(size_t)(kq + 2*i + 1)*ldn + rn] - bm) : 0.f;
    outw[i] = (unsigned)f2b(v0) | ((unsigned)f2b(v1) << 16);
  }
  uint4* d = (uint4*)(dst + (size_t)rn*256 + kq);
#pragma unroll
  for (int i = 0; i < 8; ++i) d[i] = *(uint4*)&outw[i*4];
}

// heads: rowmax + bf16 exp
__global__ __launch_bounds__(256) void prep_expHd_k(float* __restrict__ ws_f) {
  int b = blockIdx.x, t = threadIdx.x;
  int r = t >> 2, q = t & 3;
  const float* row = ws_f + OFF_HEADS + (size_t)b*HMAT + r*256 + q*64;
  float m = -INFINITY;
#pragma unroll
  for (int i = 0; i < 64; ++i) m = fmaxf(m, row[i]);
  m = fmaxf(m, __shfl_xor(m, 1));
  m = fmaxf(m, __shfl_xor(m, 2));
  if (q == 0) ws_f[OFF_AMAXHD + b*64 + r] = m;
  unsigned outw[32];
#pragma unroll
  for (int i = 0; i < 32; ++i)
    outw[i] = (unsigned)f2b(__expf(row[2*i] - m)) | ((unsigned)f2b(__expf(row[2*i + 1] - m)) << 16);
  uint4* d4 = (uint4*)((u16*)(ws_f + OFF_EXPHD) + (size_t)b*16384 + r*256 + q*64);
#pragma unroll
  for (int i = 0; i < 8; ++i) d4[i] = *(uint4*)&outw[i*4];
}

// ---------------- MFMA helpers (64x256 out, K=256, chunked K=64, XOR-swizzled LDS) ----------------
// A chunk [64 m][64 k] bf16 (128B rows), B chunk [256 n][64 k] bf16 (128B rows).
__device__ __forceinline__ void stageAB(int tid, const u16* __restrict__ gA,
                                        const u16* __restrict__ gB, int kc,
                                        char* ldsA, char* ldsB) {
#pragma unroll
  for (int p = 0; p < 2; ++p) {
    int row = p*32 + (tid >> 3), slot = tid & 7;
    uint4 v = *(const uint4*)((const char*)gA + (size_t)row*512 + kc*128 + slot*16);
    *(uint4*)(ldsA + row*128 + ((slot*16) ^ ((row & 7) << 4))) = v;
  }
#pragma unroll
  for (int p = 0; p < 8; ++p) {
    int row = p*32 + (tid >> 3), slot = tid & 7;
    uint4 v = *(const uint4*)((const char*)gB + (size_t)row*512 + kc*128 + slot*16);
    *(uint4*)(ldsB + row*128 + ((slot*16) ^ ((row & 7) << 4))) = v;
  }
}

__device__ __forceinline__ void mfma_block(int g16, int c16, int wid,
                                           const char* ldsA, const char* ldsB,
                                           f32x4 (&acc)[4][4]) {
#pragma unroll
  for (int ks = 0; ks < 2; ++ks) {
    bf16x8 af[4], bfr[4];
    int kb = ks*64 + g16*16;
#pragma unroll
    for (int mf = 0; mf < 4; ++mf) {
      int row = mf*16 + c16;
      af[mf] = *(const bf16x8*)(ldsA + row*128 + (kb ^ ((row & 7) << 4)));
    }
#pragma unroll
    for (int nf = 0; nf < 4; ++nf) {
      int n = wid*64 + nf*16 + c16;
      bfr[nf] = *(const bf16x8*)(ldsB + n*128 + (kb ^ ((n & 7) << 4)));
    }
#pragma unroll
    for (int mf = 0; mf < 4; ++mf)
#pragma unroll
      for (int nf = 0; nf < 4; ++nf)
        acc[mf][nf] = __builtin_amdgcn_mfma_f32_16x16x32_bf16(af[mf], bfr[nf], acc[mf][nf], 0, 0, 0);
  }
}

// fill: h_t = H_b (x)log Tm^j ; writes log_hidden (f32 out), expHb (bf16), amaxH
__global__ __launch_bounds__(256) void fill_mfma(float* __restrict__ ws_f, float* __restrict__ out) {
  int tt = blockIdx.x;
  int b = tt / 25, j = tt % 25;
  int tid = threadIdx.x;
  const u16* eHd = (const u16*)(ws_f + OFF_EXPHD) + (size_t)b*16384;
  float* hid = out + OUT_HIDB + (size_t)tt*HMAT;
  u16* eHb = (u16*)(ws_f + OFF_EXPHB) + (size_t)tt*16384;
  if (j == 0) {
    const float4* s4 = (const float4*)(ws_f + OFF_HEADS + (size_t)b*HMAT);
    float4* d4 = (float4*)hid;
    for (int i = tid; i < 4096; i += 256) d4[i] = s4[i];
    const uint4* s8 = (const uint4*)eHd;
    uint4* d8 = (uint4*)eHb;
    for (int i = tid; i < 2048; i += 256) d8[i] = s8[i];
    if (tid < 64) ws_f[OFF_AMAXH + tt*64 + tid] = ws_f[OFF_AMAXHD + b*64 + tid];
    return;
  }
  const u16* gB = (const u16*)(ws_f + OFF_EXPPT) + (size_t)(j - 1)*65536;
  __shared__ uint4 ldsA4[512], ldsB4[2048];
  __shared__ float sAm[64], sBm[256], redM[4][64];
  char* ldsA = (char*)ldsA4; char* ldsB = (char*)ldsB4;
  if (tid < 64) sAm[tid] = ws_f[OFF_AMAXHD + b*64 + tid];
  sBm[tid] = ws_f[OFF_BMAXP + (size_t)(j - 1)*256 + tid];
  int wid = tid >> 6, lane = tid & 63, g16 = lane >> 4, c16 = lane & 15;
  f32x4 acc[4][4];
#pragma unroll
  for (int mf = 0; mf < 4; ++mf)
#pragma unroll
    for (int nf = 0; nf < 4; ++nf) acc[mf][nf] = {0.f, 0.f, 0.f, 0.f};
  stageAB(tid, eHd, gB, 0, ldsA, ldsB);
  __syncthreads();
  for (int kc = 0; kc < 4; ++kc) {
    mfma_block(g16, c16, wid, ldsA, ldsB, acc);
    __syncthreads();
    if (kc < 3) { stageAB(tid, eHd, gB, kc + 1, ldsA, ldsB); __syncthreads(); }
  }
  float val[4][4][4];  // [mf][r][nf]
#pragma unroll
  for (int mf = 0; mf < 4; ++mf)
#pragma unroll
    for (int r = 0; r < 4; ++r) {
      int c = mf*16 + g16*4 + r;
      float amc = sAm[c];
      float mx = -INFINITY;
#pragma unroll
      for (int nf = 0; nf < 4; ++nf) {
        int n = wid*64 + nf*16 + c16;
        float v = __logf(acc[mf][nf][r]) + amc + sBm[n];
        val[mf][r][nf] = v;
        hid[c*256 + n] = v;
        mx = fmaxf(mx, v);
      }
      mx = fmaxf(mx, __shfl_xor(mx, 1));
      mx = fmaxf(mx, __shfl_xor(mx, 2));
      mx = fmaxf(mx, __shfl_xor(mx, 4));
      mx = fmaxf(mx, __shfl_xor(mx, 8));
      if (c16 == 0) redM[wid][c] = mx;
    }
  __syncthreads();
#pragma unroll
  for (int mf = 0; mf < 4; ++mf)
#pragma unroll
    for (int r = 0; r < 4; ++r) {
      int c = mf*16 + g16*4 + r;
      float gm = fmaxf(fmaxf(redM[0][c], redM[1][c]), fmaxf(redM[2][c], redM[3][c]));
      if (wid == 0 && c16 == 0) ws_f[OFF_AMAXH + tt*64 + c] = gm;
#pragma unroll
      for (int nf = 0; nf < 4; ++nf) {
        int n = wid*64 + nf*16 + c16;
        eHb[c*256 + n] = f2b(__expf(val[mf][r][nf] - gm));
      }
    }
}

// emission: log_obs_[t,c,ntile] + fused log_obs reduction
__global__ __launch_bounds__(256) void emission_mfma(const float* __restrict__ ws_f, float* __restrict__ out) {
  int tt = blockIdx.y, n0 = blockIdx.x * 256;
  int tid = threadIdx.x;
  const u16* gA = (const u16*)(ws_f + OFF_EXPHB) + (size_t)tt*16384;
  const u16* gB = (const u16*)(ws_f + OFF_EXPET) + (size_t)n0*256;
  __shared__ uint4 ldsA4[512], ldsB4[2048];
  __shared__ float sAm[64], sWexp[64], sBm[256];
  char* ldsA = (char*)ldsA4; char* ldsB = (char*)ldsB4;
  if (tid < 64) {
    float am = ws_f[OFF_AMAXH + tt*64 + tid];
    sAm[tid] = am;
    sWexp[tid] = __expf(am + ws_f[OFF_LW + tt*64 + tid]);
  }
  sBm[tid] = ws_f[OFF_BMAXE + n0 + tid];
  int wid = tid >> 6, lane = tid & 63, g16 = lane >> 4, c16 = lane & 15;
  f32x4 acc[4][4];
#pragma unroll
  for (int mf = 0; mf < 4; ++mf)
#pragma unroll
    for (int nf = 0; nf < 4; ++nf) acc[mf][nf] = {0.f, 0.f, 0.f, 0.f};
  stageAB(tid, gA, gB, 0, ldsA, ldsB);
  __syncthreads();
  for (int kc = 0; kc < 4; ++kc) {
    mfma_block(g16, c16, wid, ldsA, ldsB, acc);
    __syncthreads();
    if (kc < 3) { stageAB(tid, gA, gB, kc + 1, ldsA, ldsB); __syncthreads(); }
  }
  float* obsb = out + OUT_OBSB + (size_t)tt*CDIM*NDIM;
  float s[4] = {0.f, 0.f, 0.f, 0.f};
  int nn[4]; float bmv[4];
#pragma unroll
  for (int nf = 0; nf < 4; ++nf) {
    int nl = wid*64 + nf*16 + c16;
    nn[nf] = n0 + nl;
    bmv[nf] = sBm[nl];
  }
#pragma unroll
  for (int mf = 0; mf < 4; ++mf)
#pragma unroll
    for (int r = 0; r < 4; ++r) {
      int c = mf*16 + g16*4 + r;
      float amc = sAm[c], wc = sWexp[c];
#pragma unroll
      for (int nf = 0; nf < 4; ++nf) {
        float a = acc[mf][nf][r];
        if (nn[nf] < NDIM) obsb[(size_t)c*NDIM + nn[nf]] = __logf(a) + amc + bmv[nf];
        s[nf] += a * wc;
      }
    }
#pragma unroll
  for (int nf = 0; nf < 4; ++nf) {
    s[nf] += __shfl_xor(s[nf], 16);
    s[nf] += __shfl_xor(s[nf], 32);
  }
  if (g16 == 0) {
#pragma unroll
    for (int nf = 0; nf < 4; ++nf)
      if (nn[nf] < NDIM) out[(size_t)tt*NDIM + nn[nf]] = __logf(s[nf]) + bmv[nf];
  }
}

extern "C" void kernel_launch(void* const* d_in, const int* in_sizes, int n_in,
                              void* d_out, int out_size, void* d_ws, size_t ws_size,
                              hipStream_t stream) {
  const float* si   = (const float*)d_in[0];
  const float* cw   = (const float*)d_in[1];
  const float* em   = (const float*)d_in[2];
  const float* tm   = (const float*)d_in[3];
  const float* mask = (const float*)d_in[4];
  float* out = (float*)d_out;
  float* ws  = (float*)d_ws;
  dim3 blk(256);

  prep_rows<<<dim3(1076), blk, 0, stream>>>(si, cw, em, tm, mask, ws);

  auto powOff  = [](int j){ return (unsigned)(OFF_POW + (unsigned)j*MAT); };
  auto headOff = [](int b){ return (unsigned)(OFF_HEADS + (unsigned)b*HMAT); };
  Jobs s;

  // powers P_1..P_25 by doubling (pow[i] = Tm^(i+1); pow[0] written by prep)
  s.n = 1; s.aOff[0]=powOff(0); s.bOff[0]=powOff(0); s.cOff[0]=powOff(1); s.M[0]=256;
  logmm_kernel<<<dim3(4,4,1), blk, 0, stream>>>(ws, s);
  s.n = 2;
  s.aOff[0]=powOff(1); s.bOff[0]=powOff(0); s.cOff[0]=powOff(2); s.M[0]=256;
  s.aOff[1]=powOff(1); s.bOff[1]=powOff(1); s.cOff[1]=powOff(3); s.M[1]=256;
  logmm_kernel<<<dim3(4,4,2), blk, 0, stream>>>(ws, s);
  s.n = 4;
  for (int i=0;i<4;++i){ s.aOff[i]=powOff(3); s.bOff[i]=powOff(i); s.cOff[i]=powOff(4+i); s.M[i]=256; }
  logmm_kernel<<<dim3(4,4,4), blk, 0, stream>>>(ws, s);
  s.n = 8;
  for (int i=0;i<8;++i){ s.aOff[i]=powOff(7); s.bOff[i]=powOff(i); s.cOff[i]=powOff(8+i); s.M[i]=256; }
  logmm_kernel<<<dim3(4,4,8), blk, 0, stream>>>(ws, s);
  s.n = 9;
  for (int i=0;i<9;++i){ s.aOff[i]=powOff(15); s.bOff[i]=powOff(i); s.cOff[i]=powOff(16+i); s.M[i]=256; }
  logmm_kernel<<<dim3(4,4,9), blk, 0, stream>>>(ws, s);

  // exp-transpose of E (independent) and P (needs powers done)
  prep_expT<<<dim3(32,1), blk, 0, stream>>>(ws + OFF_LOGE, NDIM, NDIM, 0,
                                            (u16*)(ws + OFF_EXPET), 0,
                                            ws + OFF_BMAXE, 0);
  prep_expT<<<dim3(4,25), blk, 0, stream>>>(ws + OFF_POW, SDIM, SDIM, MAT,
                                            (u16*)(ws + OFF_EXPPT), 65536u,
                                            ws + OFF_BMAXP, 256u);

  // heads H_b = h0 (x) Tm^25b by doubling; R powers piggyback
  s.n = 2;
  s.aOff[0]=headOff(0); s.bOff[0]=powOff(24); s.cOff[0]=headOff(1); s.M[0]=64;
  s.aOff[1]=powOff(24); s.bOff[1]=powOff(24); s.cOff[1]=OFF_R2;     s.M[1]=256;
  logmm_kernel<<<dim3(4,4,2), blk, 0, stream>>>(ws, s);
  s.n = 3;
  s.aOff[0]=headOff(0); s.bOff[0]=OFF_R2; s.cOff[0]=headOff(2); s.M[0]=64;
  s.aOff[1]=headOff(1); s.bOff[1]=OFF_R2; s.cOff[1]=headOff(3); s.M[1]=64;
  s.aOff[2]=OFF_R2;     s.bOff[2]=OFF_R2; s.cOff[2]=OFF_R4;     s.M[2]=256;
  logmm_kernel<<<dim3(4,4,3), blk, 0, stream>>>(ws, s);
  s.n = 5;
  for (int i=0;i<4;++i){ s.aOff[i]=headOff(i); s.bOff[i]=OFF_R4; s.cOff[i]=headOff(4+i); s.M[i]=64; }
  s.aOff[4]=OFF_R4; s.bOff[4]=OFF_R4; s.cOff[4]=OFF_R8; s.M[4]=256;
  logmm_kernel<<<dim3(4,4,5), blk, 0, stream>>>(ws, s);
  s.n = 9;
  for (int i=0;i<8;++i){ s.aOff[i]=headOff(i); s.bOff[i]=OFF_R8; s.cOff[i]=headOff(8+i); s.M[i]=64; }
  s.aOff[8]=OFF_R8; s.bOff[8]=OFF_R8; s.cOff[8]=OFF_R16; s.M[8]=256;
  logmm_kernel<<<dim3(4,4,9), blk, 0, stream>>>(ws, s);
  s.n = 4;
  for (int i=0;i<4;++i){ s.aOff[i]=headOff(i); s.bOff[i]=OFF_R16; s.cOff[i]=headOff(16+i); s.M[i]=64; }
  logmm_kernel<<<dim3(4,4,4), blk, 0, stream>>>(ws, s);

  // heads -> bf16 exp + rowmax
  prep_expHd_k<<<dim3(20), blk, 0, stream>>>(ws);

  // all 500 h_t via MFMA -> log_hidden + expHb + amaxH
  fill_mfma<<<dim3(500), blk, 0, stream>>>(ws, out);

  // emission MFMA + fused C-reduction
  emission_mfma<<<dim3(8,500), blk, 0, stream>>>(ws, out);
}

// Round 4
// 521.751 us; speedup vs baseline: 2.3490x; 1.3827x over previous
//
#include <hip/hip_runtime.h>
#include <cstddef>

typedef unsigned short u16;
typedef float f32x4 __attribute__((ext_vector_type(4)));
typedef short bf16x8 __attribute__((ext_vector_type(8)));

// Problem dims
#define SDIM 256
#define CDIM 64
#define NDIM 2000
#define TDIM 500

#define MAT  (SDIM*SDIM)   // 65536
#define HMAT (CDIM*SDIM)   // 16384

// ---- workspace layout (float offsets into d_ws) ---- all PROBABILITY domain
#define OFF_POW    0u                        // [25][256][256] f32: pow[i] = Tm^(i+1)
#define OFF_R2     (OFF_POW + 25u*MAT)       // Tm^50
#define OFF_R4     (OFF_R2 + MAT)            // Tm^100
#define OFF_R8     (OFF_R4 + MAT)            // Tm^200
#define OFF_R16    (OFF_R8 + MAT)            // Tm^400
#define OFF_HEADS  (OFF_R16 + MAT)           // [20][64][256] f32: H_b = h0 @ Tm^25b
#define OFF_CW     (OFF_HEADS + 20u*HMAT)    // [500][64] f32 chain-weight probs
#define OFF_EPROB  (OFF_CW + 32000u)         // [256][2000] f32 emission probs
#define OFF_ET     (OFF_EPROB + 512000u)     // u16: E^T bf16 [2048 n][256 k]
#define OFF_PT     (OFF_ET + 262144u)        // u16: P^T bf16 [25][256 n][256 k]
#define OFF_HDB    (OFF_PT + 819200u)        // u16: heads bf16 [20][64][256]
#define OFF_HB     (OFF_HDB + 163840u)       // u16: hidden bf16 [500][64][256]
// end ~ 7.7M floats ~ 31 MB

// d_out layout: log_obs [500][2000] | log_obs_ [500][64][2000] | log_hidden [500][64][256]
#define OUT_OBSB  1000000u
#define OUT_HIDB  65000000u

__device__ __forceinline__ float waveMax(float v) {
#pragma unroll
  for (int o = 32; o >= 1; o >>= 1) v = fmaxf(v, __shfl_xor(v, o));
  return v;
}
__device__ __forceinline__ float waveSum(float v) {
#pragma unroll
  for (int o = 32; o >= 1; o >>= 1) v += __shfl_xor(v, o);
  return v;
}
__device__ __forceinline__ u16 f2b(float f) {
  union { float f; unsigned u; } x; x.f = f;
  return (u16)((x.u + 0x7fffu + ((x.u >> 16) & 1u)) >> 16);
}

// ---------------- prep: row softmax -> PROBABILITIES for all four inputs ----------------
__global__ __launch_bounds__(256) void prep_prob(
    const float* __restrict__ si, const float* __restrict__ cw,
    const float* __restrict__ em, const float* __restrict__ tm,
    const float* __restrict__ mask, float* __restrict__ ws) {
  int b = blockIdx.x;
  const float* src; const float* msk = nullptr; float* dst; int len;
  if (b < 64)       { src = si + b*SDIM;                 dst = ws + OFF_HEADS + b*SDIM; len = SDIM; }
  else if (b < 564) { int r = b - 64;  src = cw + r*64;  dst = ws + OFF_CW + r*64;      len = 64;   }
  else if (b < 820) { int r = b - 564; src = tm + (size_t)r*SDIM; dst = ws + OFF_POW + (size_t)r*SDIM; len = SDIM; }
  else              { int r = b - 820; src = em + (size_t)r*NDIM; dst = ws + OFF_EPROB + (size_t)r*NDIM; len = NDIM; msk = mask + (size_t)r*NDIM; }
  int tid = threadIdx.x;
  __shared__ float rA[4], rB[4];
  float m = -INFINITY;
  for (int i = tid; i < len; i += 256) {
    float v = src[i];
    if (msk) v += __logf(msk[i]);
    m = fmaxf(m, v);
  }
  m = waveMax(m);
  if ((tid & 63) == 0) rA[tid >> 6] = m;
  __syncthreads();
  m = fmaxf(fmaxf(rA[0], rA[1]), fmaxf(rA[2], rA[3]));
  float s = 0.f;
  for (int i = tid; i < len; i += 256) {
    float v = src[i];
    if (msk) v += __logf(msk[i]);
    s += __expf(v - m);
  }
  s = waveSum(s);
  if ((tid & 63) == 0) rB[tid >> 6] = s;
  __syncthreads();
  s = rB[0] + rB[1] + rB[2] + rB[3];
  float inv = 1.f / s;
  for (int i = tid; i < len; i += 256) {
    float v = src[i];
    if (msk) v += __logf(msk[i]);
    dst[i] = __expf(v - m) * inv;
  }
}

// ---------------- plain fp32 prob-domain GEMM tile (chain) ----------------
__device__ void gemm_tile(const float* __restrict__ A, const float* __restrict__ B,
                          float* __restrict__ C, int r0, int n0) {
  __shared__ float As[64][68];   // [k][m]
  __shared__ float Bs[64][68];   // [k][n]
  int tid = threadIdx.x;
  float acc[4][4] = {};
  int tm4 = (tid >> 4) << 2, tn4 = (tid & 15) << 2;
  for (int kc = 0; kc < 4; ++kc) {
    __syncthreads();
    {
      int rr = tid >> 2, p = tid & 3;
      const float* sA = A + (size_t)(r0 + rr)*SDIM + kc*64 + p*16;
#pragma unroll
      for (int i = 0; i < 16; ++i) As[p*16 + i][rr] = sA[i];
    }
    {
      int kk = tid >> 2, p = tid & 3;
      const float* sB = B + (size_t)(kc*64 + kk)*SDIM + n0 + p*16;
#pragma unroll
      for (int i = 0; i < 16; ++i) Bs[kk][p*16 + i] = sB[i];
    }
    __syncthreads();
#pragma unroll 8
    for (int k = 0; k < 64; ++k) {
      float4 av = *(const float4*)&As[k][tm4];
      float4 bv = *(const float4*)&Bs[k][tn4];
      float a[4] = {av.x, av.y, av.z, av.w};
      float bb[4] = {bv.x, bv.y, bv.z, bv.w};
#pragma unroll
      for (int i = 0; i < 4; ++i)
#pragma unroll
        for (int j = 0; j < 4; ++j) acc[i][j] += a[i]*bb[j];
    }
  }
#pragma unroll
  for (int i = 0; i < 4; ++i)
    *(float4*)&C[(size_t)(r0 + tm4 + i)*SDIM + n0 + tn4] =
        make_float4(acc[i][0], acc[i][1], acc[i][2], acc[i][3]);
}

struct Jobs {
  int n;
  unsigned aOff[12], bOff[12], cOff[12];
  int M[12];
};

__global__ __launch_bounds__(256) void gemm_kernel(float* __restrict__ ws, Jobs jobs) {
  int j = blockIdx.z;
  if (blockIdx.x * 64 >= jobs.M[j]) return;
  gemm_tile(ws + jobs.aOff[j], ws + jobs.bOff[j], ws + jobs.cOff[j],
            blockIdx.x * 64, blockIdx.y * 64);
}

// ---------------- coalesced tiled transpose fp32 -> bf16: dst[n][256] = src[k][n] ----------------
__global__ __launch_bounds__(256) void transpose_b16(
    const float* __restrict__ srcBase, int ldn, int nReal, unsigned srcZ,
    u16* __restrict__ dstBase, unsigned dstZ) {
  const float* src = srcBase + (size_t)blockIdx.z * srcZ;
  u16* dst = dstBase + (size_t)blockIdx.z * dstZ;
  int n0 = blockIdx.x * 64, k0 = blockIdx.y * 64;
  __shared__ float tile[64][65];   // [n_local][k_local]
  int tid = threadIdx.x;
  {
    int kk = tid >> 2, p = tid & 3;      // row k0+kk, 16 consecutive n
    const float* s = src + (size_t)(k0 + kk)*ldn + n0 + p*16;
#pragma unroll
    for (int i = 0; i < 16; ++i) {
      int n = n0 + p*16 + i;
      tile[p*16 + i][kk] = (n < nReal) ? s[i] : 0.f;
    }
  }
  __syncthreads();
  {
    int rr = tid >> 2, kq = (tid & 3) * 16;   // write n-row n0+rr, 16 k
    unsigned w[8];
#pragma unroll
    for (int i = 0; i < 8; ++i)
      w[i] = (unsigned)f2b(tile[rr][kq + 2*i]) | ((unsigned)f2b(tile[rr][kq + 2*i + 1]) << 16);
    uint4* d = (uint4*)(dst + (size_t)(n0 + rr)*256 + k0 + kq);
    d[0] = *(uint4*)&w[0];
    d[1] = *(uint4*)&w[4];
  }
}

// heads fp32 -> bf16
__global__ __launch_bounds__(256) void prep_headsb(float* __restrict__ ws_f) {
  int b = blockIdx.x, tid = threadIdx.x;
  const float* src = ws_f + OFF_HEADS + (size_t)b*HMAT;
  u16* dst = (u16*)(ws_f + OFF_HDB) + (size_t)b*HMAT;
  for (int i = tid; i < HMAT/2; i += 256) {
    float2 v = *(const float2*)(src + 2*i);
    ((unsigned*)dst)[i] = (unsigned)f2b(v.x) | ((unsigned)f2b(v.y) << 16);
  }
}

// ---------------- MFMA helpers (64x256 out, K=256, chunked K=64, XOR-swizzled LDS) ----------------
__device__ __forceinline__ void stageAB(int tid, const u16* __restrict__ gA,
                                        const u16* __restrict__ gB, int kc,
                                        char* ldsA, char* ldsB) {
#pragma unroll
  for (int p = 0; p < 2; ++p) {
    int row = p*32 + (tid >> 3), slot = tid & 7;
    uint4 v = *(const uint4*)((const char*)gA + (size_t)row*512 + kc*128 + slot*16);
    *(uint4*)(ldsA + row*128 + ((slot*16) ^ ((row & 7) << 4))) = v;
  }
#pragma unroll
  for (int p = 0; p < 8; ++p) {
    int row = p*32 + (tid >> 3), slot = tid & 7;
    uint4 v = *(const uint4*)((const char*)gB + (size_t)row*512 + kc*128 + slot*16);
    *(uint4*)(ldsB + row*128 + ((slot*16) ^ ((row & 7) << 4))) = v;
  }
}

__device__ __forceinline__ void mfma_block(int g16, int c16, int wid,
                                           const char* ldsA, const char* ldsB,
                                           f32x4 (&acc)[4][4]) {
#pragma unroll
  for (int ks = 0; ks < 2; ++ks) {
    bf16x8 af[4], bfr[4];
    int kb = ks*64 + g16*16;
#pragma unroll
    for (int mf = 0; mf < 4; ++mf) {
      int row = mf*16 + c16;
      af[mf] = *(const bf16x8*)(ldsA + row*128 + (kb ^ ((row & 7) << 4)));
    }
#pragma unroll
    for (int nf = 0; nf < 4; ++nf) {
      int n = wid*64 + nf*16 + c16;
      bfr[nf] = *(const bf16x8*)(ldsB + n*128 + (kb ^ ((n & 7) << 4)));
    }
#pragma unroll
    for (int mf = 0; mf < 4; ++mf)
#pragma unroll
      for (int nf = 0; nf < 4; ++nf)
        acc[mf][nf] = __builtin_amdgcn_mfma_f32_16x16x32_bf16(af[mf], bfr[nf], acc[mf][nf], 0, 0, 0);
  }
}

// fill: h_t = H_b @ P_j (prob domain); writes log_hidden (f32) + hidden bf16
__global__ __launch_bounds__(256) void fill_mfma(float* __restrict__ ws_f, float* __restrict__ out) {
  int tt = blockIdx.x;
  int b = tt / 25, j = tt % 25;
  int tid = threadIdx.x;
  float* hid = out + OUT_HIDB + (size_t)tt*HMAT;
  u16* hb = (u16*)(ws_f + OFF_HB) + (size_t)tt*HMAT;
  if (j == 0) {
    const float* H = ws_f + OFF_HEADS + (size_t)b*HMAT;
    for (int i = tid; i < HMAT; i += 256) {
      float v = H[i];
      hid[i] = __logf(v);
      hb[i] = f2b(v);
    }
    return;
  }
  const u16* gA = (const u16*)(ws_f + OFF_HDB) + (size_t)b*HMAT;
  const u16* gB = (const u16*)(ws_f + OFF_PT) + (size_t)(j - 1)*MAT;
  __shared__ uint4 ldsA4[512], ldsB4[2048];
  char* ldsA = (char*)ldsA4; char* ldsB = (char*)ldsB4;
  int wid = tid >> 6, lane = tid & 63, g16 = lane >> 4, c16 = lane & 15;
  f32x4 acc[4][4];
#pragma unroll
  for (int mf = 0; mf < 4; ++mf)
#pragma unroll
    for (int nf = 0; nf < 4; ++nf) acc[mf][nf] = {0.f, 0.f, 0.f, 0.f};
  stageAB(tid, gA, gB, 0, ldsA, ldsB);
  __syncthreads();
  for (int kc = 0; kc < 4; ++kc) {
    mfma_block(g16, c16, wid, ldsA, ldsB, acc);
    __syncthreads();
    if (kc < 3) { stageAB(tid, gA, gB, kc + 1, ldsA, ldsB); __syncthreads(); }
  }
#pragma unroll
  for (int mf = 0; mf < 4; ++mf)
#pragma unroll
    for (int r = 0; r < 4; ++r) {
      int c = mf*16 + g16*4 + r;
#pragma unroll
      for (int nf = 0; nf < 4; ++nf) {
        int n = wid*64 + nf*16 + c16;
        float a = acc[mf][nf][r];
        hid[c*256 + n] = __logf(a);
        hb[c*256 + n] = f2b(a);
      }
    }
}

// emission: obs = hidden @ E (prob); writes log_obs_ + fused log_obs reduction over c
__global__ __launch_bounds__(256) void emission_mfma(const float* __restrict__ ws_f, float* __restrict__ out) {
  int tt = blockIdx.y, n0 = blockIdx.x * 256;
  int tid = threadIdx.x;
  const u16* gA = (const u16*)(ws_f + OFF_HB) + (size_t)tt*HMAT;
  const u16* gB = (const u16*)(ws_f + OFF_ET) + (size_t)n0*256;
  __shared__ uint4 ldsA4[512], ldsB4[2048];
  __shared__ float sCw[64];
  char* ldsA = (char*)ldsA4; char* ldsB = (char*)ldsB4;
  if (tid < 64) sCw[tid] = ws_f[OFF_CW + tt*64 + tid];
  int wid = tid >> 6, lane = tid & 63, g16 = lane >> 4, c16 = lane & 15;
  f32x4 acc[4][4];
#pragma unroll
  for (int mf = 0; mf < 4; ++mf)
#pragma unroll
    for (int nf = 0; nf < 4; ++nf) acc[mf][nf] = {0.f, 0.f, 0.f, 0.f};
  stageAB(tid, gA, gB, 0, ldsA, ldsB);
  __syncthreads();
  for (int kc = 0; kc < 4; ++kc) {
    mfma_block(g16, c16, wid, ldsA, ldsB, acc);
    __syncthreads();
    if (kc < 3) { stageAB(tid, gA, gB, kc + 1, ldsA, ldsB); __syncthreads(); }
  }
  float* obsb = out + OUT_OBSB + (size_t)tt*CDIM*NDIM;
  float s[4] = {0.f, 0.f, 0.f, 0.f};
  int nn[4];
#pragma unroll
  for (int nf = 0; nf < 4; ++nf) nn[nf] = n0 + wid*64 + nf*16 + c16;
#pragma unroll
  for (int mf = 0; mf < 4; ++mf)
#pragma unroll
    for (int r = 0; r < 4; ++r) {
      int c = mf*16 + g16*4 + r;
      float wc = sCw[c];
#pragma unroll
      for (int nf = 0; nf < 4; ++nf) {
        float a = acc[mf][nf][r];
        if (nn[nf] < NDIM) obsb[(size_t)c*NDIM + nn[nf]] = __logf(a);
        s[nf] += a * wc;
      }
    }
#pragma unroll
  for (int nf = 0; nf < 4; ++nf) {
    s[nf] += __shfl_xor(s[nf], 16);
    s[nf] += __shfl_xor(s[nf], 32);
  }
  if (g16 == 0) {
#pragma unroll
    for (int nf = 0; nf < 4; ++nf)
      if (nn[nf] < NDIM) out[(size_t)tt*NDIM + nn[nf]] = __logf(s[nf]);
  }
}

extern "C" void kernel_launch(void* const* d_in, const int* in_sizes, int n_in,
                              void* d_out, int out_size, void* d_ws, size_t ws_size,
                              hipStream_t stream) {
  const float* si   = (const float*)d_in[0];
  const float* cw   = (const float*)d_in[1];
  const float* em   = (const float*)d_in[2];
  const float* tm   = (const float*)d_in[3];
  const float* mask = (const float*)d_in[4];
  float* out = (float*)d_out;
  float* ws  = (float*)d_ws;
  dim3 blk(256);

  prep_prob<<<dim3(1076), blk, 0, stream>>>(si, cw, em, tm, mask, ws);

  // E^T bf16 (independent of chain)
  transpose_b16<<<dim3(32, 4, 1), blk, 0, stream>>>(ws + OFF_EPROB, NDIM, NDIM, 0,
                                                    (u16*)(ws + OFF_ET), 0);

  auto powOff  = [](int j){ return (unsigned)(OFF_POW + (unsigned)j*MAT); };
  auto headOff = [](int b){ return (unsigned)(OFF_HEADS + (unsigned)b*HMAT); };
  Jobs s;

  // powers P_1..P_25 by doubling (pow[i] = Tm^(i+1); pow[0] from prep)
  s.n = 1; s.aOff[0]=powOff(0); s.bOff[0]=powOff(0); s.cOff[0]=powOff(1); s.M[0]=256;
  gemm_kernel<<<dim3(4,4,1), blk, 0, stream>>>(ws, s);
  s.n = 2;
  s.aOff[0]=powOff(1); s.bOff[0]=powOff(0); s.cOff[0]=powOff(2); s.M[0]=256;
  s.aOff[1]=powOff(1); s.bOff[1]=powOff(1); s.cOff[1]=powOff(3); s.M[1]=256;
  gemm_kernel<<<dim3(4,4,2), blk, 0, stream>>>(ws, s);
  s.n = 4;
  for (int i=0;i<4;++i){ s.aOff[i]=powOff(3); s.bOff[i]=powOff(i); s.cOff[i]=powOff(4+i); s.M[i]=256; }
  gemm_kernel<<<dim3(4,4,4), blk, 0, stream>>>(ws, s);
  s.n = 8;
  for (int i=0;i<8;++i){ s.aOff[i]=powOff(7); s.bOff[i]=powOff(i); s.cOff[i]=powOff(8+i); s.M[i]=256; }
  gemm_kernel<<<dim3(4,4,8), blk, 0, stream>>>(ws, s);
  s.n = 9;
  for (int i=0;i<9;++i){ s.aOff[i]=powOff(15); s.bOff[i]=powOff(i); s.cOff[i]=powOff(16+i); s.M[i]=256; }
  gemm_kernel<<<dim3(4,4,9), blk, 0, stream>>>(ws, s);

  // P^T bf16 for fill (needs all powers)
  transpose_b16<<<dim3(4, 4, 25), blk, 0, stream>>>(ws + OFF_POW, SDIM, SDIM, MAT,
                                                    (u16*)(ws + OFF_PT), MAT);

  // heads H_b = h0 @ Tm^25b by doubling; R powers piggyback
  s.n = 2;
  s.aOff[0]=headOff(0); s.bOff[0]=powOff(24); s.cOff[0]=headOff(1); s.M[0]=64;
  s.aOff[1]=powOff(24); s.bOff[1]=powOff(24); s.cOff[1]=OFF_R2;     s.M[1]=256;
  gemm_kernel<<<dim3(4,4,2), blk, 0, stream>>>(ws, s);
  s.n = 3;
  s.aOff[0]=headOff(0); s.bOff[0]=OFF_R2; s.cOff[0]=headOff(2); s.M[0]=64;
  s.aOff[1]=headOff(1); s.bOff[1]=OFF_R2; s.cOff[1]=headOff(3); s.M[1]=64;
  s.aOff[2]=OFF_R2;     s.bOff[2]=OFF_R2; s.cOff[2]=OFF_R4;     s.M[2]=256;
  gemm_kernel<<<dim3(4,4,3), blk, 0, stream>>>(ws, s);
  s.n = 5;
  for (int i=0;i<4;++i){ s.aOff[i]=headOff(i); s.bOff[i]=OFF_R4; s.cOff[i]=headOff(4+i); s.M[i]=64; }
  s.aOff[4]=OFF_R4; s.bOff[4]=OFF_R4; s.cOff[4]=OFF_R8; s.M[4]=256;
  gemm_kernel<<<dim3(4,4,5), blk, 0, stream>>>(ws, s);
  s.n = 9;
  for (int i=0;i<8;++i){ s.aOff[i]=headOff(i); s.bOff[i]=OFF_R8; s.cOff[i]=headOff(8+i); s.M[i]=64; }
  s.aOff[8]=OFF_R8; s.bOff[8]=OFF_R8; s.cOff[8]=OFF_R16; s.M[8]=256;
  gemm_kernel<<<dim3(4,4,9), blk, 0, stream>>>(ws, s);
  s.n = 4;
  for (int i=0;i<4;++i){ s.aOff[i]=headOff(i); s.bOff[i]=OFF_R16; s.cOff[i]=headOff(16+i); s.M[i]=64; }
  gemm_kernel<<<dim3(4,4,4), blk, 0, stream>>>(ws, s);

  // heads -> bf16
  prep_headsb<<<dim3(20), blk, 0, stream>>>(ws);

  // all 500 h_t via MFMA -> log_hidden + hidden bf16
  fill_mfma<<<dim3(500), blk, 0, stream>>>(ws, out);

  // emission MFMA + fused log_obs reduction
  emission_mfma<<<dim3(8,500), blk, 0, stream>>>(ws, out);
}